// Round 5
// baseline (419.732 us; speedup 1.0000x reference)
//
#include <hip/hip_runtime.h>
#include <hip/hip_bf16.h>
#include <math.h>

// N=50000 nodes, E=600000 edges, H=128.
#define HD 128
#define APAD 136   // LDS row stride in ushorts (+8 pad; 272B rows, 16B aligned)

typedef short bf16x8 __attribute__((ext_vector_type(8)));
typedef float f32x4 __attribute__((ext_vector_type(4)));

static __device__ __forceinline__ unsigned short f2bf(float f) {
  __hip_bfloat16 b = __float2bfloat16(f);
  return *(unsigned short*)&b;
}
static __device__ __forceinline__ float bflo(unsigned int u) {
  return __uint_as_float(u << 16);
}
static __device__ __forceinline__ float bfhi(unsigned int u) {
  return __uint_as_float(u & 0xffff0000u);
}

// ---------------------------------------------------------------------------
// K0: per-node histogram (blocks 0..eb-1) + weight-fragment pack (eb..eb+39).
// Fragment layout: F[((tile*KS+ks)*64+lane)*8+j] =
//   bf16(W[(ks*32+(lane>>4)*8+j)*128 + tile*16+(lane&15)])
// ---------------------------------------------------------------------------
__global__ __launch_bounds__(256) void k_hist_frag(
    const int* __restrict__ ei, int* __restrict__ cnt, int E, int eb,
    const float* __restrict__ enc_w, const float* __restrict__ M_w,
    const float* __restrict__ U_w,
    unsigned short* __restrict__ encf, unsigned short* __restrict__ Pf,
    unsigned short* __restrict__ Qf, unsigned short* __restrict__ Uf) {
  const int b = blockIdx.x;
  if (b < eb) {
    const int e = b * 256 + threadIdx.x;
    if (e < E) atomicAdd(&cnt[ei[E + e]], 1);
    return;
  }
  const int fb = b - eb;
  const float* W; unsigned short* F; int KS; int lb;
  if (fb < 8)       { W = enc_w + HD;     F = encf; KS = 4; lb = fb; }
  else if (fb < 16) { W = M_w;            F = Pf;   KS = 4; lb = fb - 8; }
  else if (fb < 24) { W = M_w + HD * HD;  F = Qf;   KS = 4; lb = fb - 16; }
  else              { W = U_w;            F = Uf;   KS = 8; lb = fb - 24; }
  const int gid = lb * 256 + threadIdx.x;
  const int lane = gid & 63;
  const int ks = (gid >> 6) % KS;
  const int tile = gid / (64 * KS);
  const int col = tile * 16 + (lane & 15);
  const int k0 = ks * 32 + (lane >> 4) * 8;
  unsigned short v[8];
#pragma unroll
  for (int j = 0; j < 8; ++j) v[j] = f2bf(W[(size_t)(k0 + j) * HD + col]);
  unsigned short* dst = F + ((size_t)(tile * KS + ks) * 64 + lane) * 8;
#pragma unroll
  for (int j = 0; j < 8; ++j) dst[j] = v[j];
}

// ---------------------------------------------------------------------------
// K1: single-block (1024-thread) exclusive scan over N per-node counts.
// Writes row_ptr (exclusive prefix) and cursor copy.
// ---------------------------------------------------------------------------
__global__ __launch_bounds__(1024) void k_scan1(
    const int* __restrict__ cnt, int* __restrict__ row_ptr,
    int* __restrict__ cursor, int N) {
  __shared__ int s[1024];
  const int t = threadIdx.x;
  const int per = (N + 1023) >> 10;  // 49
  const int base = t * per;
  int sum = 0;
  for (int i = 0; i < per; ++i) {
    const int idx = base + i;
    if (idx < N) sum += cnt[idx];
  }
  s[t] = sum;
  __syncthreads();
  for (int off = 1; off < 1024; off <<= 1) {
    const int v = (t >= off) ? s[t - off] : 0;
    __syncthreads();
    s[t] += v;
    __syncthreads();
  }
  int run = s[t] - sum;  // exclusive prefix of this thread's chunk
  for (int i = 0; i < per; ++i) {
    const int idx = base + i;
    if (idx < N) {
      const int c = cnt[idx];
      row_ptr[idx] = run;
      cursor[idx] = run;
      run += c;
    }
  }
}

// ---------------------------------------------------------------------------
// K2: scatter (blocks 0..eb-1) + MFMA encoder/P/Q (blocks eb..eb+N/16-1).
// Scatter: epack[pos] = (src, attr_bits) via per-node cursor (low contention).
// Encoder: z = relu(pre_h @ enc_w[1:] + x (x) enc_w[0] + enc_b) -> zg (bf16)
//          P = z @ M_w[0:128] + M_b -> Pg;  Q = z @ M_w[128:256] -> Qg
// ---------------------------------------------------------------------------
__global__ __launch_bounds__(256, 4) void k_scatter_enc(
    const int* __restrict__ ei, const float* __restrict__ edge_attr,
    int* __restrict__ cursor, int2* __restrict__ epack, int E, int eb,
    const float* __restrict__ x, const float* __restrict__ pre_h,
    const float* __restrict__ enc_w, const float* __restrict__ enc_b,
    const float* __restrict__ M_b,
    const unsigned short* __restrict__ encf, const unsigned short* __restrict__ Pf,
    const unsigned short* __restrict__ Qf,
    unsigned short* __restrict__ zg, unsigned short* __restrict__ Pg,
    unsigned short* __restrict__ Qg) {
  const int b = blockIdx.x;
  if (b < eb) {
    const int e = b * 256 + threadIdx.x;
    if (e < E) {
      const int tgt = ei[E + e];
      const int pos = atomicAdd(&cursor[tgt], 1);
      epack[pos] = make_int2(ei[e], __float_as_int(edge_attr[e]));
    }
    return;
  }
  __shared__ unsigned short phs[16 * APAD];
  __shared__ unsigned short zsh[16 * APAD];
  __shared__ float xs[16];
  const int t = threadIdx.x;
  const int n0 = (b - eb) * 16;

  {
    const int r = t >> 4, c0 = (t & 15) * 8;
    const float4 a = *(const float4*)&pre_h[(size_t)(n0 + r) * HD + c0];
    const float4 bb = *(const float4*)&pre_h[(size_t)(n0 + r) * HD + c0 + 4];
    unsigned short* d = &phs[r * APAD + c0];
    d[0] = f2bf(a.x); d[1] = f2bf(a.y); d[2] = f2bf(a.z); d[3] = f2bf(a.w);
    d[4] = f2bf(bb.x); d[5] = f2bf(bb.y); d[6] = f2bf(bb.z); d[7] = f2bf(bb.w);
  }
  if (t < 16) xs[t] = x[n0 + t];
  __syncthreads();

  const int w = t >> 6, l = t & 63;
  const int m = l & 15, q = l >> 4;

  bf16x8 af[4];
#pragma unroll
  for (int ks = 0; ks < 4; ++ks)
    af[ks] = *(const bf16x8*)&phs[m * APAD + ks * 32 + q * 8];
  f32x4 acc[2] = {{0, 0, 0, 0}, {0, 0, 0, 0}};
#pragma unroll
  for (int tt = 0; tt < 2; ++tt) {
    const int tn = 2 * w + tt;
#pragma unroll
    for (int ks = 0; ks < 4; ++ks) {
      const bf16x8 bf = *(const bf16x8*)&encf[((size_t)(tn * 4 + ks) * 64 + l) * 8];
      acc[tt] = __builtin_amdgcn_mfma_f32_16x16x32_bf16(af[ks], bf, acc[tt], 0, 0, 0);
    }
  }
#pragma unroll
  for (int tt = 0; tt < 2; ++tt) {
    const int col = (2 * w + tt) * 16 + m;
    const float bb = enc_b[col];
    const float w0 = enc_w[col];
#pragma unroll
    for (int r = 0; r < 4; ++r) {
      const int row = q * 4 + r;
      const float zv = fmaxf(acc[tt][r] + bb + xs[row] * w0, 0.0f);
      zsh[row * APAD + col] = f2bf(zv);
    }
  }
  __syncthreads();

  bf16x8 az[4];
#pragma unroll
  for (int ks = 0; ks < 4; ++ks)
    az[ks] = *(const bf16x8*)&zsh[m * APAD + ks * 32 + q * 8];
  {
    const int r = t >> 4, c0 = (t & 15) * 8;
    *(uint4*)&zg[(size_t)(n0 + r) * HD + c0] = *(const uint4*)&zsh[r * APAD + c0];
  }
  __syncthreads();

  f32x4 pacc[2] = {{0, 0, 0, 0}, {0, 0, 0, 0}};
  f32x4 qacc[2] = {{0, 0, 0, 0}, {0, 0, 0, 0}};
#pragma unroll
  for (int tt = 0; tt < 2; ++tt) {
    const int tn = 2 * w + tt;
#pragma unroll
    for (int ks = 0; ks < 4; ++ks) {
      const bf16x8 bp = *(const bf16x8*)&Pf[((size_t)(tn * 4 + ks) * 64 + l) * 8];
      const bf16x8 bq = *(const bf16x8*)&Qf[((size_t)(tn * 4 + ks) * 64 + l) * 8];
      pacc[tt] = __builtin_amdgcn_mfma_f32_16x16x32_bf16(az[ks], bp, pacc[tt], 0, 0, 0);
      qacc[tt] = __builtin_amdgcn_mfma_f32_16x16x32_bf16(az[ks], bq, qacc[tt], 0, 0, 0);
    }
  }
#pragma unroll
  for (int tt = 0; tt < 2; ++tt) {
    const int col = (2 * w + tt) * 16 + m;
    const float mb = M_b[col];
#pragma unroll
    for (int r = 0; r < 4; ++r) {
      const int row = q * 4 + r;
      phs[row * APAD + col] = f2bf(pacc[tt][r] + mb);
      zsh[row * APAD + col] = f2bf(qacc[tt][r]);
    }
  }
  __syncthreads();
  {
    const int r = t >> 4, c0 = (t & 15) * 8;
    *(uint4*)&Pg[(size_t)(n0 + r) * HD + c0] = *(const uint4*)&phs[r * APAD + c0];
    *(uint4*)&Qg[(size_t)(n0 + r) * HD + c0] = *(const uint4*)&zsh[r * APAD + c0];
  }
}

// ---------------------------------------------------------------------------
// K3: per-node gather-max + U-GEMM (MFMA) + decoder + h col sums + fused
// terminator (ticket: last block reduces).  32 nodes/block, 4 waves.
// LDS: hsh unions into ash (sync separates A-frag reads from hsh writes).
// ---------------------------------------------------------------------------
__global__ __launch_bounds__(256, 6) void k_gather_update(
    const unsigned short* __restrict__ zg, const unsigned short* __restrict__ Pg,
    const unsigned short* __restrict__ Qg, const float* __restrict__ w_attr,
    const int* __restrict__ row_ptr, const int* __restrict__ row_end,
    const int2* __restrict__ epack, const unsigned short* __restrict__ Uf,
    const float* __restrict__ U_b, const float* __restrict__ dec_w,
    const float* __restrict__ dec_b,
    float* __restrict__ h_out, float* __restrict__ y_out,
    float* __restrict__ hsumP,      // [16][128] partial slots
    unsigned int* __restrict__ ticket,
    const float* __restrict__ ter_w, const float* __restrict__ ter_b,
    float* __restrict__ ter_out, float invN, int N) {
  __shared__ unsigned short zsh[32 * APAD];
  __shared__ unsigned short ash[32 * APAD];  // agg; later reused for h (hsh)
  __shared__ int rsL[32], reL[32];
  __shared__ float hcol[HD];
  __shared__ float pr[32][8];
  __shared__ float r2[2];
  __shared__ unsigned int done;
  const int t = threadIdx.x;
  const int n0 = blockIdx.x * 32;

  {
    const int r = t >> 3, c0 = (t & 7) * 16;
    const int n = min(n0 + r, N - 1);
    *(uint4*)&zsh[r * APAD + c0]     = *(const uint4*)&zg[(size_t)n * HD + c0];
    *(uint4*)&zsh[r * APAD + c0 + 8] = *(const uint4*)&zg[(size_t)n * HD + c0 + 8];
  }
  if (t < 32) {
    const int n = min(n0 + t, N - 1);
    rsL[t] = row_ptr[n];
    reL[t] = row_end[n];
  }
  if (t < HD) hcol[t] = 0.0f;
  __syncthreads();

  const int w = t >> 6, l = t & 63;
  const float2 wav = ((const float2*)w_attr)[l];
  const unsigned short* qb = Qg + 2 * l;

  // ---- gather-max: wave w -> nodes w*8 .. w*8+7, 2 cols/lane ----
  for (int i = 0; i < 8; ++i) {
    const int r = w * 8 + i;
    const int n = n0 + r;
    const int rs = rsL[r], re = reL[r];
    float2 acc = make_float2(-INFINITY, -INFINITY);
    int e = rs;
    for (; e + 3 < re; e += 4) {
      const int2 m0 = epack[e], m1 = epack[e + 1];
      const int2 m2 = epack[e + 2], m3 = epack[e + 3];
      const unsigned q0 = *(const unsigned*)(qb + m0.x * HD);
      const unsigned q1 = *(const unsigned*)(qb + m1.x * HD);
      const unsigned q2 = *(const unsigned*)(qb + m2.x * HD);
      const unsigned q3 = *(const unsigned*)(qb + m3.x * HD);
      const float a0 = __int_as_float(m0.y), a1 = __int_as_float(m1.y);
      const float a2 = __int_as_float(m2.y), a3 = __int_as_float(m3.y);
      acc.x = fmaxf(acc.x, fmaxf(fmaxf(bflo(q0) + a0 * wav.x, bflo(q1) + a1 * wav.x),
                                 fmaxf(bflo(q2) + a2 * wav.x, bflo(q3) + a3 * wav.x)));
      acc.y = fmaxf(acc.y, fmaxf(fmaxf(bfhi(q0) + a0 * wav.y, bfhi(q1) + a1 * wav.y),
                                 fmaxf(bfhi(q2) + a2 * wav.y, bfhi(q3) + a3 * wav.y)));
    }
    for (; e < re; ++e) {
      const int2 mk = epack[e];
      const unsigned qv = *(const unsigned*)(qb + mk.x * HD);
      const float a = __int_as_float(mk.y);
      acc.x = fmaxf(acc.x, bflo(qv) + a * wav.x);
      acc.y = fmaxf(acc.y, bfhi(qv) + a * wav.y);
    }
    float2 res = make_float2(0.0f, 0.0f);
    if (re > rs) {
      const unsigned pv = *(const unsigned*)&Pg[(size_t)n * HD + 2 * l];
      res.x = fmaxf(bflo(pv) + acc.x, 0.0f);
      res.y = fmaxf(bfhi(pv) + acc.y, 0.0f);
    }
    *(unsigned*)&ash[r * APAD + 2 * l] =
        (unsigned)f2bf(res.x) | ((unsigned)f2bf(res.y) << 16);
  }
  __syncthreads();

  // ---- U-GEMM: wave w -> M-tile (w&1), cols [64*(w>>1), +64) ----
  const int mt = w & 1, nh = w >> 1;
  const int m = mt * 16 + (l & 15), q = l >> 4;
  bf16x8 afz[4], afa[4];
#pragma unroll
  for (int ks = 0; ks < 4; ++ks) {
    afz[ks] = *(const bf16x8*)&zsh[m * APAD + ks * 32 + q * 8];
    afa[ks] = *(const bf16x8*)&ash[m * APAD + ks * 32 + q * 8];
  }
  __syncthreads();  // all A-frag reads done before hsh overwrites ash

  f32x4 acc4[4] = {{0, 0, 0, 0}, {0, 0, 0, 0}, {0, 0, 0, 0}, {0, 0, 0, 0}};
#pragma unroll
  for (int tt = 0; tt < 4; ++tt) {
    const int tn = nh * 4 + tt;
#pragma unroll
    for (int ks = 0; ks < 8; ++ks) {
      const bf16x8 bf = *(const bf16x8*)&Uf[((size_t)(tn * 8 + ks) * 64 + l) * 8];
      const bf16x8 a = (ks < 4) ? afz[ks] : afa[ks - 4];
      acc4[tt] = __builtin_amdgcn_mfma_f32_16x16x32_bf16(a, bf, acc4[tt], 0, 0, 0);
    }
  }
  unsigned short* hsh = ash;  // reuse
#pragma unroll
  for (int tt = 0; tt < 4; ++tt) {
    const int col = (nh * 4 + tt) * 16 + (l & 15);
    const float ub = U_b[col];
    float s4 = 0.0f;
#pragma unroll
    for (int r = 0; r < 4; ++r) {
      const int rowl = mt * 16 + q * 4 + r;
      const int n = n0 + rowl;
      float hv = fmaxf(acc4[tt][r] + ub, 0.0f);
      if (n < N) h_out[(size_t)n * HD + col] = hv; else hv = 0.0f;
      hsh[rowl * APAD + col] = f2bf(hv);
      s4 += hv;
    }
    atomicAdd(&hcol[col], s4);
  }
  __syncthreads();

  if (t < HD) atomicAdd(&hsumP[(blockIdx.x & 15) * HD + t], hcol[t]);

  // ---- decoder: thread t -> node t>>3, cols (t&7)*16 .. +15 ----
  {
    const int r2i = t >> 3, s = t & 7;
    float part = 0.0f;
#pragma unroll
    for (int c = 0; c < 8; ++c) {
      const int kk = s * 16 + 2 * c;
      const unsigned zu = *(const unsigned*)&zsh[r2i * APAD + kk];
      const unsigned hu = *(const unsigned*)&hsh[r2i * APAD + kk];
      part += bflo(zu) * dec_w[kk] + bfhi(zu) * dec_w[kk + 1];
      part += bflo(hu) * dec_w[HD + kk] + bfhi(hu) * dec_w[HD + kk + 1];
    }
    pr[r2i][s] = part;
  }
  __syncthreads();
  if (t < 32 && n0 + t < N) {
    float d = dec_b[0];
#pragma unroll
    for (int s = 0; s < 8; ++s) d += pr[t][s];
    y_out[n0 + t] = 1.0f / (1.0f + expf(-d));
  }

  // ---- ticket: last block computes the terminator ----
  __syncthreads();
  if (t == 0) {
    __threadfence();
    done = atomicAdd(ticket, 1u);
  }
  __syncthreads();
  if (done == gridDim.x - 1) {
    if (t < HD) {
      float s = 0.0f;
#pragma unroll
      for (int k = 0; k < 16; ++k) s += atomicAdd(&hsumP[k * HD + t], 0.0f);
      float v = (s * invN) * (ter_w[t] + ter_w[HD + t]);
#pragma unroll
      for (int o = 32; o > 0; o >>= 1) v += __shfl_down(v, o);
      if ((t & 63) == 0) r2[t >> 6] = v;
    }
    __syncthreads();
    if (t == 0) ter_out[0] = r2[0] + r2[1] + ter_b[0];
  }
}

// ---------------------------------------------------------------------------
extern "C" void kernel_launch(void* const* d_in, const int* in_sizes, int n_in,
                              void* d_out, int out_size, void* d_ws, size_t ws_size,
                              hipStream_t stream) {
  const float* x        = (const float*)d_in[0];
  const float* pre_h    = (const float*)d_in[1];
  const float* edge_attr= (const float*)d_in[2];
  const float* enc_w    = (const float*)d_in[3];
  const float* enc_b    = (const float*)d_in[4];
  const float* M_w      = (const float*)d_in[5];
  const float* M_b      = (const float*)d_in[6];
  const float* U_w      = (const float*)d_in[7];
  const float* U_b      = (const float*)d_in[8];
  const float* dec_w    = (const float*)d_in[9];
  const float* dec_b    = (const float*)d_in[10];
  const float* ter_w    = (const float*)d_in[11];
  const float* ter_b    = (const float*)d_in[12];
  const int*   edge_idx = (const int*)d_in[13];

  const int N = in_sizes[0];      // 50000
  const int E = in_sizes[2];      // 600000
  const size_t NH = (size_t)N * HD;
  const int nb = (N + 31) / 32;   // 1563 gather blocks
  const int eb = (E + 255) / 256; // 2344 edge blocks

  float* out = (float*)d_out;
  float* h_out = out;             // [0, N*H)
  float* y_out = out + NH;        // [N*H, N*H+N)
  float* ter_out = out + NH + N;

  // ws: zg | Pg | Qg | epack(E int2) | encf | Pf | Qf | Uf
  //     | cnt(N) | hsumP(16*128 f32) | ticket(1) | row_ptr(N) | cursor(N)
  unsigned short* zg = (unsigned short*)d_ws;
  unsigned short* Pg = zg + NH;
  unsigned short* Qg = Pg + NH;
  int2* epack = (int2*)(Qg + NH);
  unsigned short* encf = (unsigned short*)(epack + E);
  unsigned short* Pf   = encf + 8 * 4 * 64 * 8;
  unsigned short* Qf   = Pf + 8 * 4 * 64 * 8;
  unsigned short* Uf   = Qf + 8 * 4 * 64 * 8;
  int*   cnt     = (int*)(Uf + 8 * 8 * 64 * 8);
  float* hsumP   = (float*)(cnt + N);
  unsigned int* ticket = (unsigned int*)(hsumP + 16 * HD);
  int*   row_ptr = (int*)(ticket + 1);
  int*   cursor  = row_ptr + N;

  // zero cnt + hsumP + ticket in one contiguous shot
  hipMemsetAsync(cnt, 0, ((size_t)N + 16 * HD + 1) * sizeof(int), stream);

  k_hist_frag<<<eb + 40, 256, 0, stream>>>(edge_idx, cnt, E, eb,
                                           enc_w, M_w, U_w, encf, Pf, Qf, Uf);
  k_scan1<<<1, 1024, 0, stream>>>(cnt, row_ptr, cursor, N);
  k_scatter_enc<<<eb + N / 16, 256, 0, stream>>>(
      edge_idx, edge_attr, cursor, epack, E, eb,
      x, pre_h, enc_w, enc_b, M_b, encf, Pf, Qf, zg, Pg, Qg);
  k_gather_update<<<nb, 256, 0, stream>>>(
      zg, Pg, Qg, M_w + 256 * HD, row_ptr, cursor, epack, Uf,
      U_b, dec_w, dec_b, h_out, y_out, hsumP, ticket,
      ter_w, ter_b, ter_out, 1.0f / (float)N, N);
}

// Round 6
// 307.206 us; speedup vs baseline: 1.3663x; 1.3663x over previous
//
#include <hip/hip_runtime.h>
#include <hip/hip_bf16.h>
#include <math.h>

// N=50000 nodes, E=600000 edges, H=128.
#define HD 128
#define APAD 136   // LDS row stride in ushorts (+8 pad; 272B rows, 16B aligned)

typedef short bf16x8 __attribute__((ext_vector_type(8)));
typedef float f32x4 __attribute__((ext_vector_type(4)));

static __device__ __forceinline__ unsigned short f2bf(float f) {
  __hip_bfloat16 b = __float2bfloat16(f);
  return *(unsigned short*)&b;
}
static __device__ __forceinline__ float bflo(unsigned int u) {
  return __uint_as_float(u << 16);
}
static __device__ __forceinline__ float bfhi(unsigned int u) {
  return __uint_as_float(u & 0xffff0000u);
}

// ---------------------------------------------------------------------------
// K0: per-node histogram (blocks 0..eb-1) + weight-fragment pack (eb..eb+39).
// ---------------------------------------------------------------------------
__global__ __launch_bounds__(256) void k_hist_frag(
    const int* __restrict__ ei, int* __restrict__ cnt, int E, int eb,
    const float* __restrict__ enc_w, const float* __restrict__ M_w,
    const float* __restrict__ U_w,
    unsigned short* __restrict__ encf, unsigned short* __restrict__ Pf,
    unsigned short* __restrict__ Qf, unsigned short* __restrict__ Uf) {
  const int b = blockIdx.x;
  if (b < eb) {
    const int e = b * 256 + threadIdx.x;
    if (e < E) atomicAdd(&cnt[ei[E + e]], 1);
    return;
  }
  const int fb = b - eb;
  const float* W; unsigned short* F; int KS; int lb;
  if (fb < 8)       { W = enc_w + HD;     F = encf; KS = 4; lb = fb; }
  else if (fb < 16) { W = M_w;            F = Pf;   KS = 4; lb = fb - 8; }
  else if (fb < 24) { W = M_w + HD * HD;  F = Qf;   KS = 4; lb = fb - 16; }
  else              { W = U_w;            F = Uf;   KS = 8; lb = fb - 24; }
  const int gid = lb * 256 + threadIdx.x;
  const int lane = gid & 63;
  const int ks = (gid >> 6) % KS;
  const int tile = gid / (64 * KS);
  const int col = tile * 16 + (lane & 15);
  const int k0 = ks * 32 + (lane >> 4) * 8;
  unsigned short v[8];
#pragma unroll
  for (int j = 0; j < 8; ++j) v[j] = f2bf(W[(size_t)(k0 + j) * HD + col]);
  unsigned short* dst = F + ((size_t)(tile * KS + ks) * 64 + lane) * 8;
#pragma unroll
  for (int j = 0; j < 8; ++j) dst[j] = v[j];
}

// ---------------------------------------------------------------------------
// Parallel 3-kernel exclusive scan (round-3 proven: each ~5 µs).
// ---------------------------------------------------------------------------
__global__ __launch_bounds__(256) void k_scan_block(
    const int* __restrict__ cnt, int* __restrict__ row_ptr,
    int* __restrict__ partials, int N) {
  __shared__ int s[256];
  const int t = threadIdx.x;
  const int base = blockIdx.x * 1024 + t * 4;
  int v[4], sum = 0;
#pragma unroll
  for (int i = 0; i < 4; ++i) {
    v[i] = (base + i < N) ? cnt[base + i] : 0;
    sum += v[i];
  }
  s[t] = sum;
  __syncthreads();
  for (int off = 1; off < 256; off <<= 1) {
    int xv = (t >= off) ? s[t - off] : 0;
    __syncthreads();
    if (t >= off) s[t] += xv;
    __syncthreads();
  }
  int run = s[t] - sum;
  if (t == 255) partials[blockIdx.x] = s[255];
#pragma unroll
  for (int i = 0; i < 4; ++i) {
    if (base + i < N) row_ptr[base + i] = run;
    run += v[i];
  }
}

__global__ void k_scan_partials(int* __restrict__ partials, int nb) {
  if (threadIdx.x == 0) {
    int run = 0;
    for (int i = 0; i < nb; ++i) { int v = partials[i]; partials[i] = run; run += v; }
  }
}

__global__ __launch_bounds__(256) void k_scan_add(
    int* __restrict__ row_ptr, const int* __restrict__ partials,
    int* __restrict__ cursor, int N) {
  const int base = blockIdx.x * 1024 + threadIdx.x * 4;
  const int p = partials[blockIdx.x];
#pragma unroll
  for (int i = 0; i < 4; ++i) {
    if (base + i < N) {
      int v = row_ptr[base + i] + p;
      row_ptr[base + i] = v;
      cursor[base + i] = v;
    }
  }
}

// ---------------------------------------------------------------------------
// K2: scatter (blocks 0..eb-1) + MFMA encoder/P/Q (blocks eb..eb+N/16-1).
// ---------------------------------------------------------------------------
__global__ __launch_bounds__(256, 4) void k_scatter_enc(
    const int* __restrict__ ei, const float* __restrict__ edge_attr,
    int* __restrict__ cursor, int2* __restrict__ epack, int E, int eb,
    const float* __restrict__ x, const float* __restrict__ pre_h,
    const float* __restrict__ enc_w, const float* __restrict__ enc_b,
    const float* __restrict__ M_b,
    const unsigned short* __restrict__ encf, const unsigned short* __restrict__ Pf,
    const unsigned short* __restrict__ Qf,
    unsigned short* __restrict__ zg, unsigned short* __restrict__ Pg,
    unsigned short* __restrict__ Qg) {
  const int b = blockIdx.x;
  if (b < eb) {
    const int e = b * 256 + threadIdx.x;
    if (e < E) {
      const int tgt = ei[E + e];
      const int pos = atomicAdd(&cursor[tgt], 1);
      epack[pos] = make_int2(ei[e], __float_as_int(edge_attr[e]));
    }
    return;
  }
  __shared__ unsigned short phs[16 * APAD];
  __shared__ unsigned short zsh[16 * APAD];
  __shared__ float xs[16];
  const int t = threadIdx.x;
  const int n0 = (b - eb) * 16;

  {
    const int r = t >> 4, c0 = (t & 15) * 8;
    const float4 a = *(const float4*)&pre_h[(size_t)(n0 + r) * HD + c0];
    const float4 bb = *(const float4*)&pre_h[(size_t)(n0 + r) * HD + c0 + 4];
    unsigned short* d = &phs[r * APAD + c0];
    d[0] = f2bf(a.x); d[1] = f2bf(a.y); d[2] = f2bf(a.z); d[3] = f2bf(a.w);
    d[4] = f2bf(bb.x); d[5] = f2bf(bb.y); d[6] = f2bf(bb.z); d[7] = f2bf(bb.w);
  }
  if (t < 16) xs[t] = x[n0 + t];
  __syncthreads();

  const int w = t >> 6, l = t & 63;
  const int m = l & 15, q = l >> 4;

  bf16x8 af[4];
#pragma unroll
  for (int ks = 0; ks < 4; ++ks)
    af[ks] = *(const bf16x8*)&phs[m * APAD + ks * 32 + q * 8];
  f32x4 acc[2] = {{0, 0, 0, 0}, {0, 0, 0, 0}};
#pragma unroll
  for (int tt = 0; tt < 2; ++tt) {
    const int tn = 2 * w + tt;
#pragma unroll
    for (int ks = 0; ks < 4; ++ks) {
      const bf16x8 bf = *(const bf16x8*)&encf[((size_t)(tn * 4 + ks) * 64 + l) * 8];
      acc[tt] = __builtin_amdgcn_mfma_f32_16x16x32_bf16(af[ks], bf, acc[tt], 0, 0, 0);
    }
  }
#pragma unroll
  for (int tt = 0; tt < 2; ++tt) {
    const int col = (2 * w + tt) * 16 + m;
    const float bb = enc_b[col];
    const float w0 = enc_w[col];
#pragma unroll
    for (int r = 0; r < 4; ++r) {
      const int row = q * 4 + r;
      const float zv = fmaxf(acc[tt][r] + bb + xs[row] * w0, 0.0f);
      zsh[row * APAD + col] = f2bf(zv);
    }
  }
  __syncthreads();

  bf16x8 az[4];
#pragma unroll
  for (int ks = 0; ks < 4; ++ks)
    az[ks] = *(const bf16x8*)&zsh[m * APAD + ks * 32 + q * 8];
  {
    const int r = t >> 4, c0 = (t & 15) * 8;
    *(uint4*)&zg[(size_t)(n0 + r) * HD + c0] = *(const uint4*)&zsh[r * APAD + c0];
  }
  __syncthreads();

  f32x4 pacc[2] = {{0, 0, 0, 0}, {0, 0, 0, 0}};
  f32x4 qacc[2] = {{0, 0, 0, 0}, {0, 0, 0, 0}};
#pragma unroll
  for (int tt = 0; tt < 2; ++tt) {
    const int tn = 2 * w + tt;
#pragma unroll
    for (int ks = 0; ks < 4; ++ks) {
      const bf16x8 bp = *(const bf16x8*)&Pf[((size_t)(tn * 4 + ks) * 64 + l) * 8];
      const bf16x8 bq = *(const bf16x8*)&Qf[((size_t)(tn * 4 + ks) * 64 + l) * 8];
      pacc[tt] = __builtin_amdgcn_mfma_f32_16x16x32_bf16(az[ks], bp, pacc[tt], 0, 0, 0);
      qacc[tt] = __builtin_amdgcn_mfma_f32_16x16x32_bf16(az[ks], bq, qacc[tt], 0, 0, 0);
    }
  }
#pragma unroll
  for (int tt = 0; tt < 2; ++tt) {
    const int col = (2 * w + tt) * 16 + m;
    const float mb = M_b[col];
#pragma unroll
    for (int r = 0; r < 4; ++r) {
      const int row = q * 4 + r;
      phs[row * APAD + col] = f2bf(pacc[tt][r] + mb);
      zsh[row * APAD + col] = f2bf(qacc[tt][r]);
    }
  }
  __syncthreads();
  {
    const int r = t >> 4, c0 = (t & 15) * 8;
    *(uint4*)&Pg[(size_t)(n0 + r) * HD + c0] = *(const uint4*)&phs[r * APAD + c0];
    *(uint4*)&Qg[(size_t)(n0 + r) * HD + c0] = *(const uint4*)&zsh[r * APAD + c0];
  }
}

// ---------------------------------------------------------------------------
// K3: per-node gather-max + U-GEMM (MFMA) + decoder + h col sums + fused
// terminator (ticket: last block reduces).  32 nodes/block, 4 waves.
// ---------------------------------------------------------------------------
__global__ __launch_bounds__(256, 6) void k_gather_update(
    const unsigned short* __restrict__ zg, const unsigned short* __restrict__ Pg,
    const unsigned short* __restrict__ Qg, const float* __restrict__ w_attr,
    const int* __restrict__ row_ptr, const int* __restrict__ row_end,
    const int2* __restrict__ epack, const unsigned short* __restrict__ Uf,
    const float* __restrict__ U_b, const float* __restrict__ dec_w,
    const float* __restrict__ dec_b,
    float* __restrict__ h_out, float* __restrict__ y_out,
    float* __restrict__ hsumP,      // [16][128] partial slots
    unsigned int* __restrict__ ticket,
    const float* __restrict__ ter_w, const float* __restrict__ ter_b,
    float* __restrict__ ter_out, float invN, int N) {
  __shared__ unsigned short zsh[32 * APAD];
  __shared__ unsigned short ash[32 * APAD];  // agg; later reused for h (hsh)
  __shared__ int rsL[32], reL[32];
  __shared__ float hcol[HD];
  __shared__ float pr[32][8];
  __shared__ float r2[2];
  __shared__ unsigned int done;
  const int t = threadIdx.x;
  const int n0 = blockIdx.x * 32;

  {
    const int r = t >> 3, c0 = (t & 7) * 16;
    const int n = min(n0 + r, N - 1);
    *(uint4*)&zsh[r * APAD + c0]     = *(const uint4*)&zg[(size_t)n * HD + c0];
    *(uint4*)&zsh[r * APAD + c0 + 8] = *(const uint4*)&zg[(size_t)n * HD + c0 + 8];
  }
  if (t < 32) {
    const int n = min(n0 + t, N - 1);
    rsL[t] = row_ptr[n];
    reL[t] = row_end[n];
  }
  if (t < HD) hcol[t] = 0.0f;
  __syncthreads();

  const int w = t >> 6, l = t & 63;
  const float2 wav = ((const float2*)w_attr)[l];
  const unsigned short* qb = Qg + 2 * l;

  // ---- gather-max: wave w -> nodes w*8 .. w*8+7, 2 cols/lane ----
  for (int i = 0; i < 8; ++i) {
    const int r = w * 8 + i;
    const int n = n0 + r;
    const int rs = rsL[r], re = reL[r];
    float2 acc = make_float2(-INFINITY, -INFINITY);
    int e = rs;
    for (; e + 3 < re; e += 4) {
      const int2 m0 = epack[e], m1 = epack[e + 1];
      const int2 m2 = epack[e + 2], m3 = epack[e + 3];
      const unsigned q0 = *(const unsigned*)(qb + m0.x * HD);
      const unsigned q1 = *(const unsigned*)(qb + m1.x * HD);
      const unsigned q2 = *(const unsigned*)(qb + m2.x * HD);
      const unsigned q3 = *(const unsigned*)(qb + m3.x * HD);
      const float a0 = __int_as_float(m0.y), a1 = __int_as_float(m1.y);
      const float a2 = __int_as_float(m2.y), a3 = __int_as_float(m3.y);
      acc.x = fmaxf(acc.x, fmaxf(fmaxf(bflo(q0) + a0 * wav.x, bflo(q1) + a1 * wav.x),
                                 fmaxf(bflo(q2) + a2 * wav.x, bflo(q3) + a3 * wav.x)));
      acc.y = fmaxf(acc.y, fmaxf(fmaxf(bfhi(q0) + a0 * wav.y, bfhi(q1) + a1 * wav.y),
                                 fmaxf(bfhi(q2) + a2 * wav.y, bfhi(q3) + a3 * wav.y)));
    }
    for (; e < re; ++e) {
      const int2 mk = epack[e];
      const unsigned qv = *(const unsigned*)(qb + mk.x * HD);
      const float a = __int_as_float(mk.y);
      acc.x = fmaxf(acc.x, bflo(qv) + a * wav.x);
      acc.y = fmaxf(acc.y, bfhi(qv) + a * wav.y);
    }
    float2 res = make_float2(0.0f, 0.0f);
    if (re > rs) {
      const unsigned pv = *(const unsigned*)&Pg[(size_t)n * HD + 2 * l];
      res.x = fmaxf(bflo(pv) + acc.x, 0.0f);
      res.y = fmaxf(bfhi(pv) + acc.y, 0.0f);
    }
    *(unsigned*)&ash[r * APAD + 2 * l] =
        (unsigned)f2bf(res.x) | ((unsigned)f2bf(res.y) << 16);
  }
  __syncthreads();

  // ---- U-GEMM: wave w -> M-tile (w&1), cols [64*(w>>1), +64) ----
  const int mt = w & 1, nh = w >> 1;
  const int m = mt * 16 + (l & 15), q = l >> 4;
  bf16x8 afz[4], afa[4];
#pragma unroll
  for (int ks = 0; ks < 4; ++ks) {
    afz[ks] = *(const bf16x8*)&zsh[m * APAD + ks * 32 + q * 8];
    afa[ks] = *(const bf16x8*)&ash[m * APAD + ks * 32 + q * 8];
  }
  __syncthreads();  // all A-frag reads done before hsh overwrites ash

  f32x4 acc4[4] = {{0, 0, 0, 0}, {0, 0, 0, 0}, {0, 0, 0, 0}, {0, 0, 0, 0}};
#pragma unroll
  for (int tt = 0; tt < 4; ++tt) {
    const int tn = nh * 4 + tt;
#pragma unroll
    for (int ks = 0; ks < 8; ++ks) {
      const bf16x8 bf = *(const bf16x8*)&Uf[((size_t)(tn * 8 + ks) * 64 + l) * 8];
      const bf16x8 a = (ks < 4) ? afz[ks] : afa[ks - 4];
      acc4[tt] = __builtin_amdgcn_mfma_f32_16x16x32_bf16(a, bf, acc4[tt], 0, 0, 0);
    }
  }
  unsigned short* hsh = ash;  // reuse
#pragma unroll
  for (int tt = 0; tt < 4; ++tt) {
    const int col = (nh * 4 + tt) * 16 + (l & 15);
    const float ub = U_b[col];
    float s4 = 0.0f;
#pragma unroll
    for (int r = 0; r < 4; ++r) {
      const int rowl = mt * 16 + q * 4 + r;
      const int n = n0 + rowl;
      float hv = fmaxf(acc4[tt][r] + ub, 0.0f);
      if (n < N) h_out[(size_t)n * HD + col] = hv; else hv = 0.0f;
      hsh[rowl * APAD + col] = f2bf(hv);
      s4 += hv;
    }
    atomicAdd(&hcol[col], s4);
  }
  __syncthreads();

  if (t < HD) atomicAdd(&hsumP[(blockIdx.x & 15) * HD + t], hcol[t]);

  // ---- decoder: thread t -> node t>>3, cols (t&7)*16 .. +15 ----
  {
    const int r2i = t >> 3, s = t & 7;
    float part = 0.0f;
#pragma unroll
    for (int c = 0; c < 8; ++c) {
      const int kk = s * 16 + 2 * c;
      const unsigned zu = *(const unsigned*)&zsh[r2i * APAD + kk];
      const unsigned hu = *(const unsigned*)&hsh[r2i * APAD + kk];
      part += bflo(zu) * dec_w[kk] + bfhi(zu) * dec_w[kk + 1];
      part += bflo(hu) * dec_w[HD + kk] + bfhi(hu) * dec_w[HD + kk + 1];
    }
    pr[r2i][s] = part;
  }
  __syncthreads();
  if (t < 32 && n0 + t < N) {
    float d = dec_b[0];
#pragma unroll
    for (int s = 0; s < 8; ++s) d += pr[t][s];
    y_out[n0 + t] = 1.0f / (1.0f + expf(-d));
  }

  // ---- ticket: last block computes the terminator ----
  __syncthreads();
  if (t == 0) {
    __threadfence();
    done = atomicAdd(ticket, 1u);
  }
  __syncthreads();
  if (done == gridDim.x - 1) {
    if (t < HD) {
      float s = 0.0f;
#pragma unroll
      for (int k = 0; k < 16; ++k) s += atomicAdd(&hsumP[k * HD + t], 0.0f);
      float v = (s * invN) * (ter_w[t] + ter_w[HD + t]);
#pragma unroll
      for (int o = 32; o > 0; o >>= 1) v += __shfl_down(v, o);
      if ((t & 63) == 0) r2[t >> 6] = v;
    }
    __syncthreads();
    if (t == 0) ter_out[0] = r2[0] + r2[1] + ter_b[0];
  }
}

// ---------------------------------------------------------------------------
extern "C" void kernel_launch(void* const* d_in, const int* in_sizes, int n_in,
                              void* d_out, int out_size, void* d_ws, size_t ws_size,
                              hipStream_t stream) {
  const float* x        = (const float*)d_in[0];
  const float* pre_h    = (const float*)d_in[1];
  const float* edge_attr= (const float*)d_in[2];
  const float* enc_w    = (const float*)d_in[3];
  const float* enc_b    = (const float*)d_in[4];
  const float* M_w      = (const float*)d_in[5];
  const float* M_b      = (const float*)d_in[6];
  const float* U_w      = (const float*)d_in[7];
  const float* U_b      = (const float*)d_in[8];
  const float* dec_w    = (const float*)d_in[9];
  const float* dec_b    = (const float*)d_in[10];
  const float* ter_w    = (const float*)d_in[11];
  const float* ter_b    = (const float*)d_in[12];
  const int*   edge_idx = (const int*)d_in[13];

  const int N = in_sizes[0];      // 50000
  const int E = in_sizes[2];      // 600000
  const size_t NH = (size_t)N * HD;
  const int nb = (N + 31) / 32;   // 1563 gather blocks
  const int eb = (E + 255) / 256; // 2344 edge blocks

  float* out = (float*)d_out;
  float* h_out = out;             // [0, N*H)
  float* y_out = out + NH;        // [N*H, N*H+N)
  float* ter_out = out + NH + N;

  // ws: zg | Pg | Qg | epack(E int2) | encf | Pf | Qf | Uf
  //     | cnt(N) | hsumP(16*128 f32) | ticket(1) | row_ptr(N) | cursor(N) | partials(64)
  unsigned short* zg = (unsigned short*)d_ws;
  unsigned short* Pg = zg + NH;
  unsigned short* Qg = Pg + NH;
  int2* epack = (int2*)(Qg + NH);
  unsigned short* encf = (unsigned short*)(epack + E);
  unsigned short* Pf   = encf + 8 * 4 * 64 * 8;
  unsigned short* Qf   = Pf + 8 * 4 * 64 * 8;
  unsigned short* Uf   = Qf + 8 * 4 * 64 * 8;
  int*   cnt     = (int*)(Uf + 8 * 8 * 64 * 8);
  float* hsumP   = (float*)(cnt + N);
  unsigned int* ticket = (unsigned int*)(hsumP + 16 * HD);
  int*   row_ptr = (int*)(ticket + 1);
  int*   cursor  = row_ptr + N;
  int*   partials = cursor + N;

  // zero cnt + hsumP + ticket in one contiguous shot
  hipMemsetAsync(cnt, 0, ((size_t)N + 16 * HD + 1) * sizeof(int), stream);

  const int scan_blocks = (N + 1023) / 1024;  // 49

  k_hist_frag<<<eb + 40, 256, 0, stream>>>(edge_idx, cnt, E, eb,
                                           enc_w, M_w, U_w, encf, Pf, Qf, Uf);
  k_scan_block<<<scan_blocks, 256, 0, stream>>>(cnt, row_ptr, partials, N);
  k_scan_partials<<<1, 64, 0, stream>>>(partials, scan_blocks);
  k_scan_add<<<scan_blocks, 256, 0, stream>>>(row_ptr, partials, cursor, N);
  k_scatter_enc<<<eb + N / 16, 256, 0, stream>>>(
      edge_idx, edge_attr, cursor, epack, E, eb,
      x, pre_h, enc_w, enc_b, M_b, encf, Pf, Qf, zg, Pg, Qg);
  k_gather_update<<<nb, 256, 0, stream>>>(
      zg, Pg, Qg, M_w + 256 * HD, row_ptr, cursor, epack, Uf,
      U_b, dec_w, dec_b, h_out, y_out, hsumP, ticket,
      ter_w, ter_b, ter_out, 1.0f / (float)N, N);
}

// Round 7
// 302.572 us; speedup vs baseline: 1.3872x; 1.0153x over previous
//
#include <hip/hip_runtime.h>
#include <hip/hip_bf16.h>
#include <math.h>

// N=50000 nodes, E=600000 edges, H=128.
#define HD 128
#define APAD 136   // LDS row stride in ushorts (+8 pad; 272B rows, 16B aligned)
#define CAP 512    // staged edges per 32-node block (mean ~384; global fallback)

typedef short bf16x8 __attribute__((ext_vector_type(8)));
typedef float f32x4 __attribute__((ext_vector_type(4)));

static __device__ __forceinline__ unsigned short f2bf(float f) {
  __hip_bfloat16 b = __float2bfloat16(f);
  return *(unsigned short*)&b;
}
static __device__ __forceinline__ float bflo(unsigned int u) {
  return __uint_as_float(u << 16);
}
static __device__ __forceinline__ float bfhi(unsigned int u) {
  return __uint_as_float(u & 0xffff0000u);
}

// ---------------------------------------------------------------------------
// K0: per-node histogram (blocks 0..eb-1) + weight-fragment pack (eb..eb+39).
// ---------------------------------------------------------------------------
__global__ __launch_bounds__(256) void k_hist_frag(
    const int* __restrict__ ei, int* __restrict__ cnt, int E, int eb,
    const float* __restrict__ enc_w, const float* __restrict__ M_w,
    const float* __restrict__ U_w,
    unsigned short* __restrict__ encf, unsigned short* __restrict__ Pf,
    unsigned short* __restrict__ Qf, unsigned short* __restrict__ Uf) {
  const int b = blockIdx.x;
  if (b < eb) {
    const int e = b * 256 + threadIdx.x;
    if (e < E) atomicAdd(&cnt[ei[E + e]], 1);
    return;
  }
  const int fb = b - eb;
  const float* W; unsigned short* F; int KS; int lb;
  if (fb < 8)       { W = enc_w + HD;     F = encf; KS = 4; lb = fb; }
  else if (fb < 16) { W = M_w;            F = Pf;   KS = 4; lb = fb - 8; }
  else if (fb < 24) { W = M_w + HD * HD;  F = Qf;   KS = 4; lb = fb - 16; }
  else              { W = U_w;            F = Uf;   KS = 8; lb = fb - 24; }
  const int gid = lb * 256 + threadIdx.x;
  const int lane = gid & 63;
  const int ks = (gid >> 6) % KS;
  const int tile = gid / (64 * KS);
  const int col = tile * 16 + (lane & 15);
  const int k0 = ks * 32 + (lane >> 4) * 8;
  unsigned short v[8];
#pragma unroll
  for (int j = 0; j < 8; ++j) v[j] = f2bf(W[(size_t)(k0 + j) * HD + col]);
  unsigned short* dst = F + ((size_t)(tile * KS + ks) * 64 + lane) * 8;
#pragma unroll
  for (int j = 0; j < 8; ++j) dst[j] = v[j];
}

// ---------------------------------------------------------------------------
// Parallel 3-kernel exclusive scan.
// ---------------------------------------------------------------------------
__global__ __launch_bounds__(256) void k_scan_block(
    const int* __restrict__ cnt, int* __restrict__ row_ptr,
    int* __restrict__ partials, int N) {
  __shared__ int s[256];
  const int t = threadIdx.x;
  const int base = blockIdx.x * 1024 + t * 4;
  int v[4], sum = 0;
#pragma unroll
  for (int i = 0; i < 4; ++i) {
    v[i] = (base + i < N) ? cnt[base + i] : 0;
    sum += v[i];
  }
  s[t] = sum;
  __syncthreads();
  for (int off = 1; off < 256; off <<= 1) {
    int xv = (t >= off) ? s[t - off] : 0;
    __syncthreads();
    if (t >= off) s[t] += xv;
    __syncthreads();
  }
  int run = s[t] - sum;
  if (t == 255) partials[blockIdx.x] = s[255];
#pragma unroll
  for (int i = 0; i < 4; ++i) {
    if (base + i < N) row_ptr[base + i] = run;
    run += v[i];
  }
}

__global__ void k_scan_partials(int* __restrict__ partials, int nb) {
  if (threadIdx.x == 0) {
    int run = 0;
    for (int i = 0; i < nb; ++i) { int v = partials[i]; partials[i] = run; run += v; }
  }
}

__global__ __launch_bounds__(256) void k_scan_add(
    int* __restrict__ row_ptr, const int* __restrict__ partials,
    int* __restrict__ cursor, int N) {
  const int base = blockIdx.x * 1024 + threadIdx.x * 4;
  const int p = partials[blockIdx.x];
#pragma unroll
  for (int i = 0; i < 4; ++i) {
    if (base + i < N) {
      int v = row_ptr[base + i] + p;
      row_ptr[base + i] = v;
      cursor[base + i] = v;
    }
  }
}

// ---------------------------------------------------------------------------
// K2: scatter (blocks 0..eb-1) + MFMA encoder/P/Q (blocks eb..eb+N/16-1).
// ---------------------------------------------------------------------------
__global__ __launch_bounds__(256, 4) void k_scatter_enc(
    const int* __restrict__ ei, const float* __restrict__ edge_attr,
    int* __restrict__ cursor, int2* __restrict__ epack, int E, int eb,
    const float* __restrict__ x, const float* __restrict__ pre_h,
    const float* __restrict__ enc_w, const float* __restrict__ enc_b,
    const float* __restrict__ M_b,
    const unsigned short* __restrict__ encf, const unsigned short* __restrict__ Pf,
    const unsigned short* __restrict__ Qf,
    unsigned short* __restrict__ zg, unsigned short* __restrict__ Pg,
    unsigned short* __restrict__ Qg) {
  const int b = blockIdx.x;
  if (b < eb) {
    const int e = b * 256 + threadIdx.x;
    if (e < E) {
      const int tgt = ei[E + e];
      const int pos = atomicAdd(&cursor[tgt], 1);
      epack[pos] = make_int2(ei[e], __float_as_int(edge_attr[e]));
    }
    return;
  }
  __shared__ unsigned short phs[16 * APAD];
  __shared__ unsigned short zsh[16 * APAD];
  __shared__ float xs[16];
  const int t = threadIdx.x;
  const int n0 = (b - eb) * 16;

  {
    const int r = t >> 4, c0 = (t & 15) * 8;
    const float4 a = *(const float4*)&pre_h[(size_t)(n0 + r) * HD + c0];
    const float4 bb = *(const float4*)&pre_h[(size_t)(n0 + r) * HD + c0 + 4];
    unsigned short* d = &phs[r * APAD + c0];
    d[0] = f2bf(a.x); d[1] = f2bf(a.y); d[2] = f2bf(a.z); d[3] = f2bf(a.w);
    d[4] = f2bf(bb.x); d[5] = f2bf(bb.y); d[6] = f2bf(bb.z); d[7] = f2bf(bb.w);
  }
  if (t < 16) xs[t] = x[n0 + t];
  __syncthreads();

  const int w = t >> 6, l = t & 63;
  const int m = l & 15, q = l >> 4;

  bf16x8 af[4];
#pragma unroll
  for (int ks = 0; ks < 4; ++ks)
    af[ks] = *(const bf16x8*)&phs[m * APAD + ks * 32 + q * 8];
  f32x4 acc[2] = {{0, 0, 0, 0}, {0, 0, 0, 0}};
#pragma unroll
  for (int tt = 0; tt < 2; ++tt) {
    const int tn = 2 * w + tt;
#pragma unroll
    for (int ks = 0; ks < 4; ++ks) {
      const bf16x8 bf = *(const bf16x8*)&encf[((size_t)(tn * 4 + ks) * 64 + l) * 8];
      acc[tt] = __builtin_amdgcn_mfma_f32_16x16x32_bf16(af[ks], bf, acc[tt], 0, 0, 0);
    }
  }
#pragma unroll
  for (int tt = 0; tt < 2; ++tt) {
    const int col = (2 * w + tt) * 16 + m;
    const float bb = enc_b[col];
    const float w0 = enc_w[col];
#pragma unroll
    for (int r = 0; r < 4; ++r) {
      const int row = q * 4 + r;
      const float zv = fmaxf(acc[tt][r] + bb + xs[row] * w0, 0.0f);
      zsh[row * APAD + col] = f2bf(zv);
    }
  }
  __syncthreads();

  bf16x8 az[4];
#pragma unroll
  for (int ks = 0; ks < 4; ++ks)
    az[ks] = *(const bf16x8*)&zsh[m * APAD + ks * 32 + q * 8];
  {
    const int r = t >> 4, c0 = (t & 15) * 8;
    *(uint4*)&zg[(size_t)(n0 + r) * HD + c0] = *(const uint4*)&zsh[r * APAD + c0];
  }
  __syncthreads();

  f32x4 pacc[2] = {{0, 0, 0, 0}, {0, 0, 0, 0}};
  f32x4 qacc[2] = {{0, 0, 0, 0}, {0, 0, 0, 0}};
#pragma unroll
  for (int tt = 0; tt < 2; ++tt) {
    const int tn = 2 * w + tt;
#pragma unroll
    for (int ks = 0; ks < 4; ++ks) {
      const bf16x8 bp = *(const bf16x8*)&Pf[((size_t)(tn * 4 + ks) * 64 + l) * 8];
      const bf16x8 bq = *(const bf16x8*)&Qf[((size_t)(tn * 4 + ks) * 64 + l) * 8];
      pacc[tt] = __builtin_amdgcn_mfma_f32_16x16x32_bf16(az[ks], bp, pacc[tt], 0, 0, 0);
      qacc[tt] = __builtin_amdgcn_mfma_f32_16x16x32_bf16(az[ks], bq, qacc[tt], 0, 0, 0);
    }
  }
#pragma unroll
  for (int tt = 0; tt < 2; ++tt) {
    const int col = (2 * w + tt) * 16 + m;
    const float mb = M_b[col];
#pragma unroll
    for (int r = 0; r < 4; ++r) {
      const int row = q * 4 + r;
      phs[row * APAD + col] = f2bf(pacc[tt][r] + mb);
      zsh[row * APAD + col] = f2bf(qacc[tt][r]);
    }
  }
  __syncthreads();
  {
    const int r = t >> 4, c0 = (t & 15) * 8;
    *(uint4*)&Pg[(size_t)(n0 + r) * HD + c0] = *(const uint4*)&phs[r * APAD + c0];
    *(uint4*)&Qg[(size_t)(n0 + r) * HD + c0] = *(const uint4*)&zsh[r * APAD + c0];
  }
}

// ---------------------------------------------------------------------------
// K3: per-node gather-max (eL-staged edge metadata) + U-GEMM (MFMA) +
// decoder + h col sums + fused terminator.  32 nodes/block, 4 waves.
// ---------------------------------------------------------------------------
__global__ __launch_bounds__(256, 6) void k_gather_update(
    const unsigned short* __restrict__ zg, const unsigned short* __restrict__ Pg,
    const unsigned short* __restrict__ Qg, const float* __restrict__ w_attr,
    const int* __restrict__ row_ptr, const int* __restrict__ row_end,
    const int2* __restrict__ epack, const unsigned short* __restrict__ Uf,
    const float* __restrict__ U_b, const float* __restrict__ dec_w,
    const float* __restrict__ dec_b,
    float* __restrict__ h_out, float* __restrict__ y_out,
    float* __restrict__ hsumP,      // [16][128] partial slots
    unsigned int* __restrict__ ticket,
    const float* __restrict__ ter_w, const float* __restrict__ ter_b,
    float* __restrict__ ter_out, float invN, int N) {
  __shared__ unsigned short zsh[32 * APAD];
  __shared__ unsigned short ash[32 * APAD];  // agg; later reused for h (hsh)
  __shared__ int2 eL[CAP];
  __shared__ int rsL[32], reL[32];
  __shared__ float hcol[HD];
  __shared__ float pr[32][8];
  __shared__ float r2[2];
  __shared__ unsigned int done;
  const int t = threadIdx.x;
  const int n0 = blockIdx.x * 32;

  {
    const int r = t >> 3, c0 = (t & 7) * 16;
    const int n = min(n0 + r, N - 1);
    *(uint4*)&zsh[r * APAD + c0]     = *(const uint4*)&zg[(size_t)n * HD + c0];
    *(uint4*)&zsh[r * APAD + c0 + 8] = *(const uint4*)&zg[(size_t)n * HD + c0 + 8];
  }
  if (t < 32) {
    const int n = min(n0 + t, N - 1);
    rsL[t] = row_ptr[n];
    reL[t] = row_end[n];
  }
  if (t < HD) hcol[t] = 0.0f;
  __syncthreads();
  const int estart = rsL[0];
  const int ecnt = reL[31] - estart;  // block's 32 nodes are contiguous in epack
  for (int i = t; i < min(ecnt, CAP); i += 256) eL[i] = epack[estart + i];
  __syncthreads();

  const int w = t >> 6, l = t & 63;
  const float2 wav = ((const float2*)w_attr)[l];
  const unsigned short* qb = Qg + 2 * l;

  // ---- gather-max: wave w -> nodes w*8 .. w*8+7, 2 cols/lane ----
  for (int i = 0; i < 8; ++i) {
    const int r = w * 8 + i;
    const int n = n0 + r;
    const int rs = rsL[r], re = reL[r];
    float2 acc = make_float2(-INFINITY, -INFINITY);
    int e = rs;
    for (; e + 3 < re; e += 4) {
      const int i0 = e - estart;
      const int2 m0 = (i0 + 0 < CAP) ? eL[i0 + 0] : epack[e + 0];
      const int2 m1 = (i0 + 1 < CAP) ? eL[i0 + 1] : epack[e + 1];
      const int2 m2 = (i0 + 2 < CAP) ? eL[i0 + 2] : epack[e + 2];
      const int2 m3 = (i0 + 3 < CAP) ? eL[i0 + 3] : epack[e + 3];
      const unsigned q0 = *(const unsigned*)(qb + m0.x * HD);
      const unsigned q1 = *(const unsigned*)(qb + m1.x * HD);
      const unsigned q2 = *(const unsigned*)(qb + m2.x * HD);
      const unsigned q3 = *(const unsigned*)(qb + m3.x * HD);
      const float a0 = __int_as_float(m0.y), a1 = __int_as_float(m1.y);
      const float a2 = __int_as_float(m2.y), a3 = __int_as_float(m3.y);
      acc.x = fmaxf(acc.x, fmaxf(fmaxf(bflo(q0) + a0 * wav.x, bflo(q1) + a1 * wav.x),
                                 fmaxf(bflo(q2) + a2 * wav.x, bflo(q3) + a3 * wav.x)));
      acc.y = fmaxf(acc.y, fmaxf(fmaxf(bfhi(q0) + a0 * wav.y, bfhi(q1) + a1 * wav.y),
                                 fmaxf(bfhi(q2) + a2 * wav.y, bfhi(q3) + a3 * wav.y)));
    }
    for (; e < re; ++e) {
      const int i0 = e - estart;
      const int2 mk = (i0 < CAP) ? eL[i0] : epack[e];
      const unsigned qv = *(const unsigned*)(qb + mk.x * HD);
      const float a = __int_as_float(mk.y);
      acc.x = fmaxf(acc.x, bflo(qv) + a * wav.x);
      acc.y = fmaxf(acc.y, bfhi(qv) + a * wav.y);
    }
    float2 res = make_float2(0.0f, 0.0f);
    if (re > rs) {
      const unsigned pv = *(const unsigned*)&Pg[(size_t)n * HD + 2 * l];
      res.x = fmaxf(bflo(pv) + acc.x, 0.0f);
      res.y = fmaxf(bfhi(pv) + acc.y, 0.0f);
    }
    *(unsigned*)&ash[r * APAD + 2 * l] =
        (unsigned)f2bf(res.x) | ((unsigned)f2bf(res.y) << 16);
  }
  __syncthreads();

  // ---- U-GEMM: wave w -> M-tile (w&1), cols [64*(w>>1), +64) ----
  const int mt = w & 1, nh = w >> 1;
  const int m = mt * 16 + (l & 15), q = l >> 4;
  bf16x8 afz[4], afa[4];
#pragma unroll
  for (int ks = 0; ks < 4; ++ks) {
    afz[ks] = *(const bf16x8*)&zsh[m * APAD + ks * 32 + q * 8];
    afa[ks] = *(const bf16x8*)&ash[m * APAD + ks * 32 + q * 8];
  }
  __syncthreads();  // all A-frag reads done before hsh overwrites ash

  f32x4 acc4[4] = {{0, 0, 0, 0}, {0, 0, 0, 0}, {0, 0, 0, 0}, {0, 0, 0, 0}};
#pragma unroll
  for (int tt = 0; tt < 4; ++tt) {
    const int tn = nh * 4 + tt;
#pragma unroll
    for (int ks = 0; ks < 8; ++ks) {
      const bf16x8 bf = *(const bf16x8*)&Uf[((size_t)(tn * 8 + ks) * 64 + l) * 8];
      const bf16x8 a = (ks < 4) ? afz[ks] : afa[ks - 4];
      acc4[tt] = __builtin_amdgcn_mfma_f32_16x16x32_bf16(a, bf, acc4[tt], 0, 0, 0);
    }
  }
  unsigned short* hsh = ash;  // reuse
#pragma unroll
  for (int tt = 0; tt < 4; ++tt) {
    const int col = (nh * 4 + tt) * 16 + (l & 15);
    const float ub = U_b[col];
    float s4 = 0.0f;
#pragma unroll
    for (int r = 0; r < 4; ++r) {
      const int rowl = mt * 16 + q * 4 + r;
      const int n = n0 + rowl;
      float hv = fmaxf(acc4[tt][r] + ub, 0.0f);
      if (n < N) h_out[(size_t)n * HD + col] = hv; else hv = 0.0f;
      hsh[rowl * APAD + col] = f2bf(hv);
      s4 += hv;
    }
    atomicAdd(&hcol[col], s4);
  }
  __syncthreads();

  if (t < HD) atomicAdd(&hsumP[(blockIdx.x & 15) * HD + t], hcol[t]);

  // ---- decoder: thread t -> node t>>3, cols (t&7)*16 .. +15 ----
  {
    const int r2i = t >> 3, s = t & 7;
    float part = 0.0f;
#pragma unroll
    for (int c = 0; c < 8; ++c) {
      const int kk = s * 16 + 2 * c;
      const unsigned zu = *(const unsigned*)&zsh[r2i * APAD + kk];
      const unsigned hu = *(const unsigned*)&hsh[r2i * APAD + kk];
      part += bflo(zu) * dec_w[kk] + bfhi(zu) * dec_w[kk + 1];
      part += bflo(hu) * dec_w[HD + kk] + bfhi(hu) * dec_w[HD + kk + 1];
    }
    pr[r2i][s] = part;
  }
  __syncthreads();
  if (t < 32 && n0 + t < N) {
    float d = dec_b[0];
#pragma unroll
    for (int s = 0; s < 8; ++s) d += pr[t][s];
    y_out[n0 + t] = 1.0f / (1.0f + expf(-d));
  }

  // ---- ticket: last block computes the terminator ----
  __syncthreads();
  if (t == 0) {
    __threadfence();
    done = atomicAdd(ticket, 1u);
  }
  __syncthreads();
  if (done == gridDim.x - 1) {
    if (t < HD) {
      float s = 0.0f;
#pragma unroll
      for (int k = 0; k < 16; ++k) s += atomicAdd(&hsumP[k * HD + t], 0.0f);
      float v = (s * invN) * (ter_w[t] + ter_w[HD + t]);
#pragma unroll
      for (int o = 32; o > 0; o >>= 1) v += __shfl_down(v, o);
      if ((t & 63) == 0) r2[t >> 6] = v;
    }
    __syncthreads();
    if (t == 0) ter_out[0] = r2[0] + r2[1] + ter_b[0];
  }
}

// ---------------------------------------------------------------------------
extern "C" void kernel_launch(void* const* d_in, const int* in_sizes, int n_in,
                              void* d_out, int out_size, void* d_ws, size_t ws_size,
                              hipStream_t stream) {
  const float* x        = (const float*)d_in[0];
  const float* pre_h    = (const float*)d_in[1];
  const float* edge_attr= (const float*)d_in[2];
  const float* enc_w    = (const float*)d_in[3];
  const float* enc_b    = (const float*)d_in[4];
  const float* M_w      = (const float*)d_in[5];
  const float* M_b      = (const float*)d_in[6];
  const float* U_w      = (const float*)d_in[7];
  const float* U_b      = (const float*)d_in[8];
  const float* dec_w    = (const float*)d_in[9];
  const float* dec_b    = (const float*)d_in[10];
  const float* ter_w    = (const float*)d_in[11];
  const float* ter_b    = (const float*)d_in[12];
  const int*   edge_idx = (const int*)d_in[13];

  const int N = in_sizes[0];      // 50000
  const int E = in_sizes[2];      // 600000
  const size_t NH = (size_t)N * HD;
  const int nb = (N + 31) / 32;   // 1563 gather blocks
  const int eb = (E + 255) / 256; // 2344 edge blocks

  float* out = (float*)d_out;
  float* h_out = out;             // [0, N*H)
  float* y_out = out + NH;        // [N*H, N*H+N)
  float* ter_out = out + NH + N;

  // ws: zg | Pg | Qg | epack(E int2) | encf | Pf | Qf | Uf
  //     | cnt(N) | hsumP(16*128 f32) | ticket(1) | row_ptr(N) | cursor(N) | partials(64)
  unsigned short* zg = (unsigned short*)d_ws;
  unsigned short* Pg = zg + NH;
  unsigned short* Qg = Pg + NH;
  int2* epack = (int2*)(Qg + NH);
  unsigned short* encf = (unsigned short*)(epack + E);
  unsigned short* Pf   = encf + 8 * 4 * 64 * 8;
  unsigned short* Qf   = Pf + 8 * 4 * 64 * 8;
  unsigned short* Uf   = Qf + 8 * 4 * 64 * 8;
  int*   cnt     = (int*)(Uf + 8 * 8 * 64 * 8);
  float* hsumP   = (float*)(cnt + N);
  unsigned int* ticket = (unsigned int*)(hsumP + 16 * HD);
  int*   row_ptr = (int*)(ticket + 1);
  int*   cursor  = row_ptr + N;
  int*   partials = cursor + N;

  // zero cnt + hsumP + ticket in one contiguous shot
  hipMemsetAsync(cnt, 0, ((size_t)N + 16 * HD + 1) * sizeof(int), stream);

  const int scan_blocks = (N + 1023) / 1024;  // 49

  k_hist_frag<<<eb + 40, 256, 0, stream>>>(edge_idx, cnt, E, eb,
                                           enc_w, M_w, U_w, encf, Pf, Qf, Uf);
  k_scan_block<<<scan_blocks, 256, 0, stream>>>(cnt, row_ptr, partials, N);
  k_scan_partials<<<1, 64, 0, stream>>>(partials, scan_blocks);
  k_scan_add<<<scan_blocks, 256, 0, stream>>>(row_ptr, partials, cursor, N);
  k_scatter_enc<<<eb + N / 16, 256, 0, stream>>>(
      edge_idx, edge_attr, cursor, epack, E, eb,
      x, pre_h, enc_w, enc_b, M_b, encf, Pf, Qf, zg, Pg, Qg);
  k_gather_update<<<nb, 256, 0, stream>>>(
      zg, Pg, Qg, M_w + 256 * HD, row_ptr, cursor, epack, Uf,
      U_b, dec_w, dec_b, h_out, y_out, hsumP, ticket,
      ter_w, ter_b, ter_out, 1.0f / (float)N, N);
}

// Round 8
// 289.988 us; speedup vs baseline: 1.4474x; 1.0434x over previous
//
#include <hip/hip_runtime.h>
#include <hip/hip_bf16.h>
#include <math.h>

// N=50000 nodes, E=600000 edges, H=128.
#define HD 128
#define APAD 136   // LDS row stride in ushorts (+8 pad; 272B rows, 16B aligned)
#define CAP 512    // staged edges per 32-node block (mean ~384; global fallback)

typedef short bf16x8 __attribute__((ext_vector_type(8)));
typedef float f32x4 __attribute__((ext_vector_type(4)));

static __device__ __forceinline__ unsigned short f2bf(float f) {
  __hip_bfloat16 b = __float2bfloat16(f);
  return *(unsigned short*)&b;
}
static __device__ __forceinline__ float bflo(unsigned int u) {
  return __uint_as_float(u << 16);
}
static __device__ __forceinline__ float bfhi(unsigned int u) {
  return __uint_as_float(u & 0xffff0000u);
}

// ---------------------------------------------------------------------------
// K0: per-node histogram (blocks 0..eb-1) + weight-fragment pack (eb..eb+39).
// ---------------------------------------------------------------------------
__global__ __launch_bounds__(256) void k_hist_frag(
    const int* __restrict__ ei, int* __restrict__ cnt, int E, int eb,
    const float* __restrict__ enc_w, const float* __restrict__ M_w,
    const float* __restrict__ U_w,
    unsigned short* __restrict__ encf, unsigned short* __restrict__ Pf,
    unsigned short* __restrict__ Qf, unsigned short* __restrict__ Uf) {
  const int b = blockIdx.x;
  if (b < eb) {
    const int e = b * 256 + threadIdx.x;
    if (e < E) atomicAdd(&cnt[ei[E + e]], 1);
    return;
  }
  const int fb = b - eb;
  const float* W; unsigned short* F; int KS; int lb;
  if (fb < 8)       { W = enc_w + HD;     F = encf; KS = 4; lb = fb; }
  else if (fb < 16) { W = M_w;            F = Pf;   KS = 4; lb = fb - 8; }
  else if (fb < 24) { W = M_w + HD * HD;  F = Qf;   KS = 4; lb = fb - 16; }
  else              { W = U_w;            F = Uf;   KS = 8; lb = fb - 24; }
  const int gid = lb * 256 + threadIdx.x;
  const int lane = gid & 63;
  const int ks = (gid >> 6) % KS;
  const int tile = gid / (64 * KS);
  const int col = tile * 16 + (lane & 15);
  const int k0 = ks * 32 + (lane >> 4) * 8;
  unsigned short v[8];
#pragma unroll
  for (int j = 0; j < 8; ++j) v[j] = f2bf(W[(size_t)(k0 + j) * HD + col]);
  unsigned short* dst = F + ((size_t)(tile * KS + ks) * 64 + lane) * 8;
#pragma unroll
  for (int j = 0; j < 8; ++j) dst[j] = v[j];
}

// ---------------------------------------------------------------------------
// Parallel 3-kernel exclusive scan.
// ---------------------------------------------------------------------------
__global__ __launch_bounds__(256) void k_scan_block(
    const int* __restrict__ cnt, int* __restrict__ row_ptr,
    int* __restrict__ partials, int N) {
  __shared__ int s[256];
  const int t = threadIdx.x;
  const int base = blockIdx.x * 1024 + t * 4;
  int v[4], sum = 0;
#pragma unroll
  for (int i = 0; i < 4; ++i) {
    v[i] = (base + i < N) ? cnt[base + i] : 0;
    sum += v[i];
  }
  s[t] = sum;
  __syncthreads();
  for (int off = 1; off < 256; off <<= 1) {
    int xv = (t >= off) ? s[t - off] : 0;
    __syncthreads();
    if (t >= off) s[t] += xv;
    __syncthreads();
  }
  int run = s[t] - sum;
  if (t == 255) partials[blockIdx.x] = s[255];
#pragma unroll
  for (int i = 0; i < 4; ++i) {
    if (base + i < N) row_ptr[base + i] = run;
    run += v[i];
  }
}

__global__ void k_scan_partials(int* __restrict__ partials, int nb) {
  if (threadIdx.x == 0) {
    int run = 0;
    for (int i = 0; i < nb; ++i) { int v = partials[i]; partials[i] = run; run += v; }
  }
}

__global__ __launch_bounds__(256) void k_scan_add(
    int* __restrict__ row_ptr, const int* __restrict__ partials,
    int* __restrict__ cursor, int N) {
  const int base = blockIdx.x * 1024 + threadIdx.x * 4;
  const int p = partials[blockIdx.x];
#pragma unroll
  for (int i = 0; i < 4; ++i) {
    if (base + i < N) {
      int v = row_ptr[base + i] + p;
      row_ptr[base + i] = v;
      cursor[base + i] = v;
    }
  }
}

// ---------------------------------------------------------------------------
// K2: scatter (blocks 0..eb-1) + MFMA encoder/P/Q (blocks eb..eb+N/16-1).
// ---------------------------------------------------------------------------
__global__ __launch_bounds__(256, 4) void k_scatter_enc(
    const int* __restrict__ ei, const float* __restrict__ edge_attr,
    int* __restrict__ cursor, int2* __restrict__ epack, int E, int eb,
    const float* __restrict__ x, const float* __restrict__ pre_h,
    const float* __restrict__ enc_w, const float* __restrict__ enc_b,
    const float* __restrict__ M_b,
    const unsigned short* __restrict__ encf, const unsigned short* __restrict__ Pf,
    const unsigned short* __restrict__ Qf,
    unsigned short* __restrict__ zg, unsigned short* __restrict__ Pg,
    unsigned short* __restrict__ Qg) {
  const int b = blockIdx.x;
  if (b < eb) {
    const int e = b * 256 + threadIdx.x;
    if (e < E) {
      const int tgt = ei[E + e];
      const int pos = atomicAdd(&cursor[tgt], 1);
      epack[pos] = make_int2(ei[e], __float_as_int(edge_attr[e]));
    }
    return;
  }
  __shared__ unsigned short phs[16 * APAD];
  __shared__ unsigned short zsh[16 * APAD];
  __shared__ float xs[16];
  const int t = threadIdx.x;
  const int n0 = (b - eb) * 16;

  {
    const int r = t >> 4, c0 = (t & 15) * 8;
    const float4 a = *(const float4*)&pre_h[(size_t)(n0 + r) * HD + c0];
    const float4 bb = *(const float4*)&pre_h[(size_t)(n0 + r) * HD + c0 + 4];
    unsigned short* d = &phs[r * APAD + c0];
    d[0] = f2bf(a.x); d[1] = f2bf(a.y); d[2] = f2bf(a.z); d[3] = f2bf(a.w);
    d[4] = f2bf(bb.x); d[5] = f2bf(bb.y); d[6] = f2bf(bb.z); d[7] = f2bf(bb.w);
  }
  if (t < 16) xs[t] = x[n0 + t];
  __syncthreads();

  const int w = t >> 6, l = t & 63;
  const int m = l & 15, q = l >> 4;

  bf16x8 af[4];
#pragma unroll
  for (int ks = 0; ks < 4; ++ks)
    af[ks] = *(const bf16x8*)&phs[m * APAD + ks * 32 + q * 8];
  f32x4 acc[2] = {{0, 0, 0, 0}, {0, 0, 0, 0}};
#pragma unroll
  for (int tt = 0; tt < 2; ++tt) {
    const int tn = 2 * w + tt;
#pragma unroll
    for (int ks = 0; ks < 4; ++ks) {
      const bf16x8 bf = *(const bf16x8*)&encf[((size_t)(tn * 4 + ks) * 64 + l) * 8];
      acc[tt] = __builtin_amdgcn_mfma_f32_16x16x32_bf16(af[ks], bf, acc[tt], 0, 0, 0);
    }
  }
#pragma unroll
  for (int tt = 0; tt < 2; ++tt) {
    const int col = (2 * w + tt) * 16 + m;
    const float bb = enc_b[col];
    const float w0 = enc_w[col];
#pragma unroll
    for (int r = 0; r < 4; ++r) {
      const int row = q * 4 + r;
      const float zv = fmaxf(acc[tt][r] + bb + xs[row] * w0, 0.0f);
      zsh[row * APAD + col] = f2bf(zv);
    }
  }
  __syncthreads();

  bf16x8 az[4];
#pragma unroll
  for (int ks = 0; ks < 4; ++ks)
    az[ks] = *(const bf16x8*)&zsh[m * APAD + ks * 32 + q * 8];
  {
    const int r = t >> 4, c0 = (t & 15) * 8;
    *(uint4*)&zg[(size_t)(n0 + r) * HD + c0] = *(const uint4*)&zsh[r * APAD + c0];
  }
  __syncthreads();

  f32x4 pacc[2] = {{0, 0, 0, 0}, {0, 0, 0, 0}};
  f32x4 qacc[2] = {{0, 0, 0, 0}, {0, 0, 0, 0}};
#pragma unroll
  for (int tt = 0; tt < 2; ++tt) {
    const int tn = 2 * w + tt;
#pragma unroll
    for (int ks = 0; ks < 4; ++ks) {
      const bf16x8 bp = *(const bf16x8*)&Pf[((size_t)(tn * 4 + ks) * 64 + l) * 8];
      const bf16x8 bq = *(const bf16x8*)&Qf[((size_t)(tn * 4 + ks) * 64 + l) * 8];
      pacc[tt] = __builtin_amdgcn_mfma_f32_16x16x32_bf16(az[ks], bp, pacc[tt], 0, 0, 0);
      qacc[tt] = __builtin_amdgcn_mfma_f32_16x16x32_bf16(az[ks], bq, qacc[tt], 0, 0, 0);
    }
  }
#pragma unroll
  for (int tt = 0; tt < 2; ++tt) {
    const int col = (2 * w + tt) * 16 + m;
    const float mb = M_b[col];
#pragma unroll
    for (int r = 0; r < 4; ++r) {
      const int row = q * 4 + r;
      phs[row * APAD + col] = f2bf(pacc[tt][r] + mb);
      zsh[row * APAD + col] = f2bf(qacc[tt][r]);
    }
  }
  __syncthreads();
  {
    const int r = t >> 4, c0 = (t & 15) * 8;
    *(uint4*)&Pg[(size_t)(n0 + r) * HD + c0] = *(const uint4*)&phs[r * APAD + c0];
    *(uint4*)&Qg[(size_t)(n0 + r) * HD + c0] = *(const uint4*)&zsh[r * APAD + c0];
  }
}

// ---------------------------------------------------------------------------
// K3: per-node gather-max (8-deep ILP, select-free fast path) + U-GEMM +
// decoder + h col sums + fused terminator.  32 nodes/block, 4 waves.
// ---------------------------------------------------------------------------
__global__ __launch_bounds__(256, 6) void k_gather_update(
    const unsigned short* __restrict__ zg, const unsigned short* __restrict__ Pg,
    const unsigned short* __restrict__ Qg, const float* __restrict__ w_attr,
    const int* __restrict__ row_ptr, const int* __restrict__ row_end,
    const int2* __restrict__ epack, const unsigned short* __restrict__ Uf,
    const float* __restrict__ U_b, const float* __restrict__ dec_w,
    const float* __restrict__ dec_b,
    float* __restrict__ h_out, float* __restrict__ y_out,
    float* __restrict__ hsumP,      // [16][128] partial slots
    unsigned int* __restrict__ ticket,
    const float* __restrict__ ter_w, const float* __restrict__ ter_b,
    float* __restrict__ ter_out, float invN, int N) {
  __shared__ unsigned short zsh[32 * APAD];
  __shared__ unsigned short ash[32 * APAD];  // agg; later reused for h (hsh)
  __shared__ int2 eL[CAP];
  __shared__ int rsL[32], reL[32];
  __shared__ float hcol[HD];
  __shared__ float pr[32][8];
  __shared__ float r2[2];
  __shared__ unsigned int done;
  const int t = threadIdx.x;
  const int n0 = blockIdx.x * 32;

  {
    const int r = t >> 3, c0 = (t & 7) * 16;
    const int n = min(n0 + r, N - 1);
    *(uint4*)&zsh[r * APAD + c0]     = *(const uint4*)&zg[(size_t)n * HD + c0];
    *(uint4*)&zsh[r * APAD + c0 + 8] = *(const uint4*)&zg[(size_t)n * HD + c0 + 8];
  }
  if (t < 32) {
    const int n = min(n0 + t, N - 1);
    rsL[t] = row_ptr[n];
    reL[t] = row_end[n];
  }
  if (t < HD) hcol[t] = 0.0f;
  __syncthreads();
  const int estart = rsL[0];
  const int ecnt = reL[31] - estart;  // block's 32 nodes are contiguous in epack
  for (int i = t; i < min(ecnt, CAP); i += 256) eL[i] = epack[estart + i];
  __syncthreads();

  const int w = t >> 6, l = t & 63;
  const float2 wav = ((const float2*)w_attr)[l];
  const unsigned short* qb = Qg + 2 * l;

  // ---- gather-max: wave w -> nodes w*8 .. w*8+7, 2 cols/lane ----
  for (int i = 0; i < 8; ++i) {
    const int r = w * 8 + i;
    const int n = n0 + r;
    const int rs = rsL[r], re = reL[r];
    const unsigned pv = *(const unsigned*)&Pg[(size_t)n * HD + 2 * l];  // prefetch
    float2 acc = make_float2(-INFINITY, -INFINITY);
    if (re - estart <= CAP) {
      // fast path: this node's edges fully staged in LDS, no per-edge selects
      int i0 = rs - estart;
      const int i1 = re - estart;
      for (; i0 + 7 < i1; i0 += 8) {
        int2 mm[8];
#pragma unroll
        for (int jj = 0; jj < 8; ++jj) mm[jj] = eL[i0 + jj];
        unsigned qq[8];
#pragma unroll
        for (int jj = 0; jj < 8; ++jj)
          qq[jj] = *(const unsigned*)(qb + mm[jj].x * HD);
#pragma unroll
        for (int jj = 0; jj < 8; ++jj) {
          const float a = __int_as_float(mm[jj].y);
          acc.x = fmaxf(acc.x, bflo(qq[jj]) + a * wav.x);
          acc.y = fmaxf(acc.y, bfhi(qq[jj]) + a * wav.y);
        }
      }
      for (; i0 + 3 < i1; i0 += 4) {
        int2 mm[4];
#pragma unroll
        for (int jj = 0; jj < 4; ++jj) mm[jj] = eL[i0 + jj];
        unsigned qq[4];
#pragma unroll
        for (int jj = 0; jj < 4; ++jj)
          qq[jj] = *(const unsigned*)(qb + mm[jj].x * HD);
#pragma unroll
        for (int jj = 0; jj < 4; ++jj) {
          const float a = __int_as_float(mm[jj].y);
          acc.x = fmaxf(acc.x, bflo(qq[jj]) + a * wav.x);
          acc.y = fmaxf(acc.y, bfhi(qq[jj]) + a * wav.y);
        }
      }
      for (; i0 < i1; ++i0) {
        const int2 mk = eL[i0];
        const unsigned qv = *(const unsigned*)(qb + mk.x * HD);
        const float a = __int_as_float(mk.y);
        acc.x = fmaxf(acc.x, bflo(qv) + a * wav.x);
        acc.y = fmaxf(acc.y, bfhi(qv) + a * wav.y);
      }
    } else {
      // slow path (rare): read epack directly from global
      for (int e = rs; e < re; ++e) {
        const int2 mk = epack[e];
        const unsigned qv = *(const unsigned*)(qb + mk.x * HD);
        const float a = __int_as_float(mk.y);
        acc.x = fmaxf(acc.x, bflo(qv) + a * wav.x);
        acc.y = fmaxf(acc.y, bfhi(qv) + a * wav.y);
      }
    }
    float2 res = make_float2(0.0f, 0.0f);
    if (re > rs) {
      res.x = fmaxf(bflo(pv) + acc.x, 0.0f);
      res.y = fmaxf(bfhi(pv) + acc.y, 0.0f);
    }
    *(unsigned*)&ash[r * APAD + 2 * l] =
        (unsigned)f2bf(res.x) | ((unsigned)f2bf(res.y) << 16);
  }
  __syncthreads();

  // ---- U-GEMM: wave w -> M-tile (w&1), cols [64*(w>>1), +64) ----
  const int mt = w & 1, nh = w >> 1;
  const int m = mt * 16 + (l & 15), q = l >> 4;
  bf16x8 afz[4], afa[4];
#pragma unroll
  for (int ks = 0; ks < 4; ++ks) {
    afz[ks] = *(const bf16x8*)&zsh[m * APAD + ks * 32 + q * 8];
    afa[ks] = *(const bf16x8*)&ash[m * APAD + ks * 32 + q * 8];
  }
  __syncthreads();  // all A-frag reads done before hsh overwrites ash

  f32x4 acc4[4] = {{0, 0, 0, 0}, {0, 0, 0, 0}, {0, 0, 0, 0}, {0, 0, 0, 0}};
#pragma unroll
  for (int tt = 0; tt < 4; ++tt) {
    const int tn = nh * 4 + tt;
#pragma unroll
    for (int ks = 0; ks < 8; ++ks) {
      const bf16x8 bf = *(const bf16x8*)&Uf[((size_t)(tn * 8 + ks) * 64 + l) * 8];
      const bf16x8 a = (ks < 4) ? afz[ks] : afa[ks - 4];
      acc4[tt] = __builtin_amdgcn_mfma_f32_16x16x32_bf16(a, bf, acc4[tt], 0, 0, 0);
    }
  }
  unsigned short* hsh = ash;  // reuse
#pragma unroll
  for (int tt = 0; tt < 4; ++tt) {
    const int col = (nh * 4 + tt) * 16 + (l & 15);
    const float ub = U_b[col];
    float s4 = 0.0f;
#pragma unroll
    for (int r = 0; r < 4; ++r) {
      const int rowl = mt * 16 + q * 4 + r;
      const int n = n0 + rowl;
      float hv = fmaxf(acc4[tt][r] + ub, 0.0f);
      if (n < N) h_out[(size_t)n * HD + col] = hv; else hv = 0.0f;
      hsh[rowl * APAD + col] = f2bf(hv);
      s4 += hv;
    }
    atomicAdd(&hcol[col], s4);
  }
  __syncthreads();

  if (t < HD) atomicAdd(&hsumP[(blockIdx.x & 15) * HD + t], hcol[t]);

  // ---- decoder: thread t -> node t>>3, cols (t&7)*16 .. +15 ----
  {
    const int r2i = t >> 3, s = t & 7;
    float part = 0.0f;
#pragma unroll
    for (int c = 0; c < 8; ++c) {
      const int kk = s * 16 + 2 * c;
      const unsigned zu = *(const unsigned*)&zsh[r2i * APAD + kk];
      const unsigned hu = *(const unsigned*)&hsh[r2i * APAD + kk];
      part += bflo(zu) * dec_w[kk] + bfhi(zu) * dec_w[kk + 1];
      part += bflo(hu) * dec_w[HD + kk] + bfhi(hu) * dec_w[HD + kk + 1];
    }
    pr[r2i][s] = part;
  }
  __syncthreads();
  if (t < 32 && n0 + t < N) {
    float d = dec_b[0];
#pragma unroll
    for (int s = 0; s < 8; ++s) d += pr[t][s];
    y_out[n0 + t] = 1.0f / (1.0f + expf(-d));
  }

  // ---- ticket: last block computes the terminator ----
  __syncthreads();
  if (t == 0) {
    __threadfence();
    done = atomicAdd(ticket, 1u);
  }
  __syncthreads();
  if (done == gridDim.x - 1) {
    if (t < HD) {
      float s = 0.0f;
#pragma unroll
      for (int k = 0; k < 16; ++k) s += atomicAdd(&hsumP[k * HD + t], 0.0f);
      float v = (s * invN) * (ter_w[t] + ter_w[HD + t]);
#pragma unroll
      for (int o = 32; o > 0; o >>= 1) v += __shfl_down(v, o);
      if ((t & 63) == 0) r2[t >> 6] = v;
    }
    __syncthreads();
    if (t == 0) ter_out[0] = r2[0] + r2[1] + ter_b[0];
  }
}

// ---------------------------------------------------------------------------
extern "C" void kernel_launch(void* const* d_in, const int* in_sizes, int n_in,
                              void* d_out, int out_size, void* d_ws, size_t ws_size,
                              hipStream_t stream) {
  const float* x        = (const float*)d_in[0];
  const float* pre_h    = (const float*)d_in[1];
  const float* edge_attr= (const float*)d_in[2];
  const float* enc_w    = (const float*)d_in[3];
  const float* enc_b    = (const float*)d_in[4];
  const float* M_w      = (const float*)d_in[5];
  const float* M_b      = (const float*)d_in[6];
  const float* U_w      = (const float*)d_in[7];
  const float* U_b      = (const float*)d_in[8];
  const float* dec_w    = (const float*)d_in[9];
  const float* dec_b    = (const float*)d_in[10];
  const float* ter_w    = (const float*)d_in[11];
  const float* ter_b    = (const float*)d_in[12];
  const int*   edge_idx = (const int*)d_in[13];

  const int N = in_sizes[0];      // 50000
  const int E = in_sizes[2];      // 600000
  const size_t NH = (size_t)N * HD;
  const int nb = (N + 31) / 32;   // 1563 gather blocks
  const int eb = (E + 255) / 256; // 2344 edge blocks

  float* out = (float*)d_out;
  float* h_out = out;             // [0, N*H)
  float* y_out = out + NH;        // [N*H, N*H+N)
  float* ter_out = out + NH + N;

  // ws: zg | Pg | Qg | epack(E int2) | encf | Pf | Qf | Uf
  //     | cnt(N) | hsumP(16*128 f32) | ticket(1) | row_ptr(N) | cursor(N) | partials(64)
  unsigned short* zg = (unsigned short*)d_ws;
  unsigned short* Pg = zg + NH;
  unsigned short* Qg = Pg + NH;
  int2* epack = (int2*)(Qg + NH);
  unsigned short* encf = (unsigned short*)(epack + E);
  unsigned short* Pf   = encf + 8 * 4 * 64 * 8;
  unsigned short* Qf   = Pf + 8 * 4 * 64 * 8;
  unsigned short* Uf   = Qf + 8 * 4 * 64 * 8;
  int*   cnt     = (int*)(Uf + 8 * 8 * 64 * 8);
  float* hsumP   = (float*)(cnt + N);
  unsigned int* ticket = (unsigned int*)(hsumP + 16 * HD);
  int*   row_ptr = (int*)(ticket + 1);
  int*   cursor  = row_ptr + N;
  int*   partials = cursor + N;

  // zero cnt + hsumP + ticket in one contiguous shot
  hipMemsetAsync(cnt, 0, ((size_t)N + 16 * HD + 1) * sizeof(int), stream);

  const int scan_blocks = (N + 1023) / 1024;  // 49

  k_hist_frag<<<eb + 40, 256, 0, stream>>>(edge_idx, cnt, E, eb,
                                           enc_w, M_w, U_w, encf, Pf, Qf, Uf);
  k_scan_block<<<scan_blocks, 256, 0, stream>>>(cnt, row_ptr, partials, N);
  k_scan_partials<<<1, 64, 0, stream>>>(partials, scan_blocks);
  k_scan_add<<<scan_blocks, 256, 0, stream>>>(row_ptr, partials, cursor, N);
  k_scatter_enc<<<eb + N / 16, 256, 0, stream>>>(
      edge_idx, edge_attr, cursor, epack, E, eb,
      x, pre_h, enc_w, enc_b, M_b, encf, Pf, Qf, zg, Pg, Qg);
  k_gather_update<<<nb, 256, 0, stream>>>(
      zg, Pg, Qg, M_w + 256 * HD, row_ptr, cursor, epack, Uf,
      U_b, dec_w, dec_b, h_out, y_out, hsumP, ticket,
      ter_w, ter_b, ter_out, 1.0f / (float)N, N);
}